// Round 1
// baseline (730.458 us; speedup 1.0000x reference)
//
#include <hip/hip_runtime.h>

#define D     384
#define E     769      // 1 + 2*D
#define NTOK  4096
#define BPN   32       // B*P
#define NROWS (BPN*NTOK)

typedef short s16x8 __attribute__((ext_vector_type(8)));
typedef float f32x4 __attribute__((ext_vector_type(4)));

__device__ __forceinline__ unsigned short f2bf(float f){
  unsigned int u = __builtin_bit_cast(unsigned int, f);
  u += 0x7FFFu + ((u >> 16) & 1u);          // round-to-nearest-even
  return (unsigned short)(u >> 16);
}

// ---------------- K0: pack wq; build wvT[j][c], woT[o][j] in bf16 ----------------
__global__ void k0_prep(const float* __restrict__ wqkv, const float* __restrict__ wout,
                        float* __restrict__ wq, unsigned short* __restrict__ wvT,
                        unsigned short* __restrict__ woT){
  int tid = blockIdx.x*256 + threadIdx.x;
  if (tid < D) wq[tid] = wqkv[(size_t)tid*E];              // w_qkv[:,0]
  if (tid < D*D){
    int a = tid/D, c = tid%D;
    wvT[tid] = f2bf(wqkv[(size_t)c*E + 385 + a]);          // wvT[j][c] = wv[c][j]
    woT[tid] = f2bf(wout[(size_t)c*D + a]);                // woT[o][j] = wout[j][o]
  }
}

// ---------------- K1: q[row] = H[row,:] . wq ----------------
__global__ void k1_query(const float* __restrict__ H, const float* __restrict__ wq,
                         float* __restrict__ q){
  int row  = blockIdx.x*4 + (threadIdx.x >> 6);
  int lane = threadIdx.x & 63;
  const float* hr = H + (size_t)row*D;
  float a = 0.f;
  #pragma unroll
  for (int it=0; it<3; ++it){
    int k = lane*2 + it*128;
    float2 h = *reinterpret_cast<const float2*>(hr + k);
    float2 w = *reinterpret_cast<const float2*>(wq + k);
    a += h.x*w.x + h.y*w.y;
  }
  #pragma unroll
  for (int off=32; off; off>>=1) a += __shfl_xor(a, off, 64);
  if (lane==0) q[row] = a;
}

// ---------------- K2: s = softmax(q) over the 4096 tokens of each (b,p) ----------------
__global__ void k2_softmax(const float* __restrict__ q, float* __restrict__ s){
  __shared__ float red[256];
  int bp = blockIdx.x, t = threadIdx.x;
  const float* qb = q + (size_t)bp*NTOK;
  float v[16]; float m = -3.4e38f;
  #pragma unroll
  for (int i=0;i<16;++i){ v[i] = qb[t + i*256]; m = fmaxf(m, v[i]); }
  red[t] = m; __syncthreads();
  for (int o=128;o;o>>=1){ if (t<o) red[t] = fmaxf(red[t], red[t+o]); __syncthreads(); }
  m = red[0]; __syncthreads();
  float sum = 0.f;
  #pragma unroll
  for (int i=0;i<16;++i){ v[i] = __expf(v[i]-m); sum += v[i]; }
  red[t] = sum; __syncthreads();
  for (int o=128;o;o>>=1){ if (t<o) red[t] += red[t+o]; __syncthreads(); }
  float inv = 1.f/red[0];
  #pragma unroll
  for (int i=0;i<16;++i) s[(size_t)bp*NTOK + t + i*256] = v[i]*inv;
}

// ---------------- K3: partial[bp][ch][c] = sum over 128 rows of s_n * H[n][c] ----------------
__global__ void k3_wsum(const float* __restrict__ H, const float* __restrict__ s,
                        float* __restrict__ partial){
  int ch = blockIdx.x, bp = blockIdx.y, c = threadIdx.x;
  size_t base = (size_t)bp*NTOK + (size_t)ch*128;
  float acc = 0.f;
  #pragma unroll 4
  for (int r=0;r<128;++r)
    acc += s[base+r] * H[(base+r)*D + c];
  partial[((size_t)bp*32 + ch)*D + c] = acc;
}

// ---------------- K4: reduce partials; cv[bp][j] = (sum_n s_n H_n) @ wk + bk ----------------
__global__ void k4_cv(const float* __restrict__ partial, const float* __restrict__ wqkv,
                      const float* __restrict__ bqkv, float* __restrict__ cv){
  __shared__ float sn[D];
  int bp = blockIdx.x, j = threadIdx.x;
  float t = 0.f;
  #pragma unroll 4
  for (int ch=0; ch<32; ++ch) t += partial[((size_t)bp*32+ch)*D + j];
  sn[j] = t; __syncthreads();
  float c = bqkv[1+j];
  #pragma unroll 4
  for (int k=0;k<D;++k) c += sn[k]*wqkv[(size_t)k*E + 1 + j];
  cv[(size_t)bp*D + j] = c;
}

// ---------------- K5: per 64-row block: out = relu(A@wv + bv)*cv @ Wout + bout ----------------
#define BM 64
#define PJ 392   // padded LDS row length (bf16 elems): 784 B, 16B-aligned, breaks bank conflicts

__global__ void k5_main(const float* __restrict__ H, const unsigned short* __restrict__ wvT,
                        const unsigned short* __restrict__ woT, const float* __restrict__ cv,
                        const float* __restrict__ bqkv, const float* __restrict__ bout,
                        float* __restrict__ out){
  __shared__ unsigned short As[BM*PJ];   // 50176 B; reused as R-buffer for GEMM2
  const int bp = blockIdx.y;
  const int m0 = blockIdx.x*BM;
  const size_t rowbase = (size_t)bp*NTOK + m0;
  const float* A = H + rowbase*D;
  const int t = threadIdx.x;

  // stage H rows (fp32) -> bf16 LDS, fully coalesced (block reads 96 KB contiguous)
  #pragma unroll
  for (int i=0;i<24;++i){
    int fi = t + i*256;
    int row = fi/96, k4 = fi%96;
    float4 v = *reinterpret_cast<const float4*>(A + (size_t)fi*4);
    ushort4 b;
    b.x=f2bf(v.x); b.y=f2bf(v.y); b.z=f2bf(v.z); b.w=f2bf(v.w);
    *reinterpret_cast<ushort4*>(&As[row*PJ + k4*4]) = b;
  }
  __syncthreads();

  const int wave = t>>6, lane = t&63;
  const int l15 = lane&15, l4 = lane>>4;
  const int n0 = wave*96;                 // each of 4 waves owns 96 output cols

  f32x4 acc[4][6] = {};
  // GEMM1: v = A @ wv   (B-frags straight from L2-resident wvT; no barriers in K-loop)
  for (int kt=0; kt<12; ++kt){
    s16x8 a[4], b[6];
    #pragma unroll
    for (int m=0;m<4;++m)
      a[m] = *reinterpret_cast<const s16x8*>(&As[(m*16+l15)*PJ + kt*32 + l4*8]);
    #pragma unroll
    for (int n=0;n<6;++n)
      b[n] = *reinterpret_cast<const s16x8*>(&wvT[(size_t)(n0+n*16+l15)*D + kt*32 + l4*8]);
    #pragma unroll
    for (int m=0;m<4;++m)
      #pragma unroll
      for (int n=0;n<6;++n)
        acc[m][n] = __builtin_amdgcn_mfma_f32_16x16x32_bf16(a[m], b[n], acc[m][n], 0,0,0);
  }
  __syncthreads();   // everyone done reading As before overwrite

  // epilogue1: r = relu(v + bv) * cv  -> bf16 back into As (as R[64][384])
  #pragma unroll
  for (int n=0;n<6;++n){
    int col = n0 + n*16 + l15;
    float bv  = bqkv[385+col];
    float cvv = cv[(size_t)bp*D + col];
    #pragma unroll
    for (int m=0;m<4;++m){
      #pragma unroll
      for (int r=0;r<4;++r){
        int row = m*16 + l4*4 + r;
        float v = acc[m][n][r] + bv;
        v = v > 0.f ? v*cvv : 0.f;
        As[row*PJ + col] = f2bf(v);
      }
    }
  }
  // reset accumulators (reuse same registers for GEMM2)
  #pragma unroll
  for (int m=0;m<4;++m)
    #pragma unroll
    for (int n=0;n<6;++n)
      acc[m][n] = (f32x4){0.f,0.f,0.f,0.f};
  __syncthreads();

  // GEMM2: out = R @ Wout
  for (int kt=0; kt<12; ++kt){
    s16x8 a[4], b[6];
    #pragma unroll
    for (int m=0;m<4;++m)
      a[m] = *reinterpret_cast<const s16x8*>(&As[(m*16+l15)*PJ + kt*32 + l4*8]);
    #pragma unroll
    for (int n=0;n<6;++n)
      b[n] = *reinterpret_cast<const s16x8*>(&woT[(size_t)(n0+n*16+l15)*D + kt*32 + l4*8]);
    #pragma unroll
    for (int m=0;m<4;++m)
      #pragma unroll
      for (int n=0;n<6;++n)
        acc[m][n] = __builtin_amdgcn_mfma_f32_16x16x32_bf16(a[m], b[n], acc[m][n], 0,0,0);
  }

  // epilogue2: + bout, store fp32
  #pragma unroll
  for (int n=0;n<6;++n){
    int col = n0 + n*16 + l15;
    float bo = bout[col];
    #pragma unroll
    for (int m=0;m<4;++m)
      #pragma unroll
      for (int r=0;r<4;++r){
        int row = m*16 + l4*4 + r;
        out[(rowbase+row)*D + col] = acc[m][n][r] + bo;
      }
  }
}

extern "C" void kernel_launch(void* const* d_in, const int* in_sizes, int n_in,
                              void* d_out, int out_size, void* d_ws, size_t ws_size,
                              hipStream_t stream){
  const float* H    = (const float*)d_in[0];
  const float* wqkv = (const float*)d_in[1];
  const float* bqkv = (const float*)d_in[2];
  const float* wout = (const float*)d_in[3];
  const float* bout = (const float*)d_in[4];
  float* out = (float*)d_out;

  char* ws = (char*)d_ws;
  float*          q       = (float*)(ws + 0x000000);   // 131072 f = 512 KB
  float*          s       = (float*)(ws + 0x080000);   // 512 KB
  float*          partial = (float*)(ws + 0x100000);   // 32*32*384 f = 1.5 MB
  float*          cv      = (float*)(ws + 0x280000);   // 12288 f
  float*          wq      = (float*)(ws + 0x290000);   // 384 f
  unsigned short* wvT     = (unsigned short*)(ws + 0x291000);  // 288 KB
  unsigned short* woT     = (unsigned short*)(ws + 0x2D9000);  // 288 KB  (end ~3.3 MB)

  hipLaunchKernelGGL(k0_prep,    dim3(576),          dim3(256), 0, stream, wqkv, wout, wq, wvT, woT);
  hipLaunchKernelGGL(k1_query,   dim3(NROWS/4),      dim3(256), 0, stream, H, wq, q);
  hipLaunchKernelGGL(k2_softmax, dim3(BPN),          dim3(256), 0, stream, q, s);
  hipLaunchKernelGGL(k3_wsum,    dim3(32, BPN),      dim3(384), 0, stream, H, s, partial);
  hipLaunchKernelGGL(k4_cv,      dim3(BPN),          dim3(384), 0, stream, partial, wqkv, bqkv, cv);
  hipLaunchKernelGGL(k5_main,    dim3(NTOK/BM, BPN), dim3(256), 0, stream, H, wvT, woT, cv, bqkv, bout, out);
}

// Round 2
// 342.243 us; speedup vs baseline: 2.1343x; 2.1343x over previous
//
#include <hip/hip_runtime.h>

#define D     384
#define E     769      // 1 + 2*D
#define NTOK  4096
#define BPN   32       // B*P
#define NROWS (BPN*NTOK)

typedef short s16x8 __attribute__((ext_vector_type(8)));
typedef float f32x4 __attribute__((ext_vector_type(4)));

__device__ __forceinline__ unsigned short f2bf(float f){
  unsigned int u = __builtin_bit_cast(unsigned int, f);
  u += 0x7FFFu + ((u >> 16) & 1u);          // round-to-nearest-even
  return (unsigned short)(u >> 16);
}

// ---------------- K0: pack wq; build FRAGMENT-ORDERED bf16 weights ----------------
// frag idx f = ((ntile*12 + kt)*64 + lane)*8 + pos ; lane = l4*16+l15
// element   = W[k = kt*32 + l4*8 + pos][col = ntile*16 + l15]
__global__ void k0_prep(const float* __restrict__ wqkv, const float* __restrict__ wout,
                        float* __restrict__ wq, unsigned short* __restrict__ wvF,
                        unsigned short* __restrict__ woF){
  int tid = blockIdx.x*256 + threadIdx.x;     // 0 .. 147455
  if (tid < D) wq[tid] = wqkv[(size_t)tid*E];              // w_qkv[:,0]
  if (tid < 24*12*64*8){
    int pos = tid & 7;
    int lane = (tid >> 3) & 63;
    int kt  = (tid >> 9) % 12;
    int nt  = tid / 6144;
    int l15 = lane & 15, l4 = lane >> 4;
    int col = nt*16 + l15;
    int k   = kt*32 + l4*8 + pos;
    wvF[tid] = f2bf(wqkv[(size_t)k*E + 385 + col]);        // wv[k][col]
    woF[tid] = f2bf(wout[(size_t)k*D + col]);              // wout[k][col]
  }
}

// ---------------- K1: q[row] = H[row,:] . wq ----------------
__global__ void k1_query(const float* __restrict__ H, const float* __restrict__ wq,
                         float* __restrict__ q){
  int row  = blockIdx.x*4 + (threadIdx.x >> 6);
  int lane = threadIdx.x & 63;
  const float* hr = H + (size_t)row*D;
  float a = 0.f;
  #pragma unroll
  for (int it=0; it<3; ++it){
    int k = lane*2 + it*128;
    float2 h = *reinterpret_cast<const float2*>(hr + k);
    float2 w = *reinterpret_cast<const float2*>(wq + k);
    a += h.x*w.x + h.y*w.y;
  }
  #pragma unroll
  for (int off=32; off; off>>=1) a += __shfl_xor(a, off, 64);
  if (lane==0) q[row] = a;
}

// ---------------- K2: s = softmax(q) over the 4096 tokens of each (b,p) ----------------
__global__ void k2_softmax(const float* __restrict__ q, float* __restrict__ s){
  __shared__ float red[256];
  int bp = blockIdx.x, t = threadIdx.x;
  const float* qb = q + (size_t)bp*NTOK;
  float v[16]; float m = -3.4e38f;
  #pragma unroll
  for (int i=0;i<16;++i){ v[i] = qb[t + i*256]; m = fmaxf(m, v[i]); }
  red[t] = m; __syncthreads();
  for (int o=128;o;o>>=1){ if (t<o) red[t] = fmaxf(red[t], red[t+o]); __syncthreads(); }
  m = red[0]; __syncthreads();
  float sum = 0.f;
  #pragma unroll
  for (int i=0;i<16;++i){ v[i] = __expf(v[i]-m); sum += v[i]; }
  red[t] = sum; __syncthreads();
  for (int o=128;o;o>>=1){ if (t<o) red[t] += red[t+o]; __syncthreads(); }
  float inv = 1.f/red[0];
  #pragma unroll
  for (int i=0;i<16;++i) s[(size_t)bp*NTOK + t + i*256] = v[i]*inv;
}

// ---------------- K3: partial[bp][ch][c] = sum over 128 rows of s_n * H[n][c] ----------------
__global__ void k3_wsum(const float* __restrict__ H, const float* __restrict__ s,
                        float* __restrict__ partial){
  int ch = blockIdx.x, bp = blockIdx.y, c = threadIdx.x;
  size_t base = (size_t)bp*NTOK + (size_t)ch*128;
  float acc = 0.f;
  #pragma unroll 4
  for (int r=0;r<128;++r)
    acc += s[base+r] * H[(base+r)*D + c];
  partial[((size_t)bp*32 + ch)*D + c] = acc;
}

// ---------------- K4: reduce partials; cv[bp][j] = (sum_n s_n H_n) @ wk + bk ----------------
__global__ void k4_cv(const float* __restrict__ partial, const float* __restrict__ wqkv,
                      const float* __restrict__ bqkv, float* __restrict__ cv){
  __shared__ float sn[D];
  int bp = blockIdx.x, j = threadIdx.x;
  float t = 0.f;
  #pragma unroll 4
  for (int ch=0; ch<32; ++ch) t += partial[((size_t)bp*32+ch)*D + j];
  sn[j] = t; __syncthreads();
  float c = bqkv[1+j];
  #pragma unroll 4
  for (int k=0;k<D;++k) c += sn[k]*wqkv[(size_t)k*E + 1 + j];
  cv[(size_t)bp*D + j] = c;
}

// ---------------- K5: per 64-row block: out = relu(A@wv + bv)*cv @ Wout + bout ----------------
#define BM 64

__global__ __launch_bounds__(256, 3)
void k5_main(const float* __restrict__ H, const unsigned short* __restrict__ wvF,
             const unsigned short* __restrict__ woF, const float* __restrict__ cv,
             const float* __restrict__ bqkv, const float* __restrict__ bout,
             float* __restrict__ out){
  // fragment-ordered LDS: As[((m*12+kt)*64 + lane)*8 + pos] = A[m*16+l15][kt*32+l4*8+pos]
  __shared__ unsigned short As[BM*D];    // 49152 B; reused as R-buffer for GEMM2
  const int bp = blockIdx.y;
  const int m0 = blockIdx.x*BM;
  const size_t rowbase = (size_t)bp*NTOK + m0;
  const float* A = H + rowbase*D;
  const int t = threadIdx.x;

  // stage H (fp32, coalesced) -> bf16 LDS in FRAGMENT order
  // chunk c handles frag elems c*4..c*4+3 = one float4 from H
  #pragma unroll
  for (int i=0;i<24;++i){
    int c = t + i*256;                   // 0..6143
    int idx8 = c >> 1;
    int l15v = idx8 & 15;
    int l4v  = (idx8 >> 4) & 3;
    int ktv  = (idx8 >> 6) % 12;
    int mv   = idx8 / 768;
    float4 v = *reinterpret_cast<const float4*>(
        A + (size_t)(mv*16 + l15v)*D + ktv*32 + l4v*8 + (c&1)*4);
    ushort4 b;
    b.x=f2bf(v.x); b.y=f2bf(v.y); b.z=f2bf(v.z); b.w=f2bf(v.w);
    *reinterpret_cast<ushort4*>(&As[c*4]) = b;
  }
  __syncthreads();

  const int wave = t>>6, lane = t&63;
  const int l15 = lane&15, l4 = lane>>4;
  const int n0 = wave*96;                      // each of 4 waves owns 96 output cols
  const unsigned short* wvW = wvF + (size_t)wave*6*12*512;   // this wave's 6 n-tiles
  const unsigned short* woW = woF + (size_t)wave*6*12*512;

  f32x4 acc[4][6] = {};
  // GEMM1: v = A @ wv  — b-frags are contiguous 1KB/wave coalesced loads from L2
  #pragma unroll
  for (int kt=0; kt<12; ++kt){
    s16x8 a[4], b[6];
    #pragma unroll
    for (int m=0;m<4;++m)
      a[m] = *reinterpret_cast<const s16x8*>(&As[((m*12+kt)*64 + lane)*8]);
    #pragma unroll
    for (int n=0;n<6;++n)
      b[n] = *reinterpret_cast<const s16x8*>(&wvW[((size_t)(n*12+kt)*64 + lane)*8]);
    #pragma unroll
    for (int m=0;m<4;++m)
      #pragma unroll
      for (int n=0;n<6;++n)
        acc[m][n] = __builtin_amdgcn_mfma_f32_16x16x32_bf16(a[m], b[n], acc[m][n], 0,0,0);
  }
  __syncthreads();   // everyone done reading As before overwrite

  // epilogue1: r = relu(v + bv) * cv  -> bf16 back into As in FRAGMENT order
  #pragma unroll
  for (int n=0;n<6;++n){
    int col = n0 + n*16 + l15;
    float bv  = bqkv[385+col];
    float cvv = cv[(size_t)bp*D + col];
    int kt2 = col >> 5;
    int l42 = (col >> 3) & 3;
    int pos2 = col & 7;
    #pragma unroll
    for (int m=0;m<4;++m){
      #pragma unroll
      for (int r=0;r<4;++r){
        int row = l4*4 + r;              // within m-tile
        float v = acc[m][n][r] + bv;
        v = v > 0.f ? v*cvv : 0.f;
        As[((m*12+kt2)*64 + l42*16 + row)*8 + pos2] = f2bf(v);
      }
    }
  }
  // reset accumulators (reuse same registers for GEMM2)
  #pragma unroll
  for (int m=0;m<4;++m)
    #pragma unroll
    for (int n=0;n<6;++n)
      acc[m][n] = (f32x4){0.f,0.f,0.f,0.f};
  __syncthreads();

  // GEMM2: out = R @ Wout
  #pragma unroll
  for (int kt=0; kt<12; ++kt){
    s16x8 a[4], b[6];
    #pragma unroll
    for (int m=0;m<4;++m)
      a[m] = *reinterpret_cast<const s16x8*>(&As[((m*12+kt)*64 + lane)*8]);
    #pragma unroll
    for (int n=0;n<6;++n)
      b[n] = *reinterpret_cast<const s16x8*>(&woW[((size_t)(n*12+kt)*64 + lane)*8]);
    #pragma unroll
    for (int m=0;m<4;++m)
      #pragma unroll
      for (int n=0;n<6;++n)
        acc[m][n] = __builtin_amdgcn_mfma_f32_16x16x32_bf16(a[m], b[n], acc[m][n], 0,0,0);
  }

  // epilogue2: + bout, store fp32 (16 lanes x 64B contiguous per instr)
  #pragma unroll
  for (int n=0;n<6;++n){
    int col = n0 + n*16 + l15;
    float bo = bout[col];
    #pragma unroll
    for (int m=0;m<4;++m)
      #pragma unroll
      for (int r=0;r<4;++r){
        int row = m*16 + l4*4 + r;
        out[(rowbase+row)*D + col] = acc[m][n][r] + bo;
      }
  }
}

extern "C" void kernel_launch(void* const* d_in, const int* in_sizes, int n_in,
                              void* d_out, int out_size, void* d_ws, size_t ws_size,
                              hipStream_t stream){
  const float* H    = (const float*)d_in[0];
  const float* wqkv = (const float*)d_in[1];
  const float* bqkv = (const float*)d_in[2];
  const float* wout = (const float*)d_in[3];
  const float* bout = (const float*)d_in[4];
  float* out = (float*)d_out;

  char* ws = (char*)d_ws;
  float*          q       = (float*)(ws + 0x000000);   // 512 KB
  float*          s       = (float*)(ws + 0x080000);   // 512 KB
  float*          partial = (float*)(ws + 0x100000);   // 1.5 MB
  float*          cv      = (float*)(ws + 0x280000);   // 48 KB slot
  float*          wq      = (float*)(ws + 0x290000);   // 1.5 KB slot
  unsigned short* wvF     = (unsigned short*)(ws + 0x291000);  // 288 KB
  unsigned short* woF     = (unsigned short*)(ws + 0x2D9000);  // 288 KB

  hipLaunchKernelGGL(k0_prep,    dim3(576),          dim3(256), 0, stream, wqkv, wout, wq, wvF, woF);
  hipLaunchKernelGGL(k1_query,   dim3(NROWS/4),      dim3(256), 0, stream, H, wq, q);
  hipLaunchKernelGGL(k2_softmax, dim3(BPN),          dim3(256), 0, stream, q, s);
  hipLaunchKernelGGL(k3_wsum,    dim3(32, BPN),      dim3(384), 0, stream, H, s, partial);
  hipLaunchKernelGGL(k4_cv,      dim3(BPN),          dim3(384), 0, stream, partial, wqkv, bqkv, cv);
  hipLaunchKernelGGL(k5_main,    dim3(NTOK/BM, BPN), dim3(256), 0, stream, H, wvF, woF, cv, bqkv, bout, out);
}